// Round 1
// baseline (816.322 us; speedup 1.0000x reference)
//
#include <hip/hip_runtime.h>

#define NUM_CLASSES 100000
#define NUM_FEATURES 256
#define BATCH 1024
#define SCALARF 30.0f
#define EPSF 1e-12f

typedef __attribute__((ext_vector_type(4))) float float4v;
typedef __attribute__((ext_vector_type(8))) short short8;   // 8 x bf16 (4 VGPRs)
typedef __attribute__((ext_vector_type(4))) short short4v;  // 4 x bf16 (8 B)

static __device__ inline short f2bf(float f) {
    // round-to-nearest-even fp32 -> bf16 (inputs are finite randn; NaN path irrelevant)
    unsigned u = __builtin_bit_cast(unsigned, f);
    unsigned r = (u + 0x7FFFu + ((u >> 16) & 1u)) >> 16;
    return (short)r;
}

static __device__ inline float wave_reduce_sum(float s) {
#pragma unroll
    for (int off = 32; off > 0; off >>= 1) s += __shfl_xor(s, off, 64);
    return s;
}

// ---------------------------------------------------------------------------
// K1: normalize x rows -> xn (fp32) and xnb (bf16); echo targets as float32.
// One wave per row; lane holds 4 contiguous floats.
__global__ __launch_bounds__(64) void xnorm_kernel(const float* __restrict__ x,
                                                   const int* __restrict__ tgt,
                                                   float* __restrict__ xn,
                                                   short* __restrict__ xnb,
                                                   float* __restrict__ out_tgt) {
    int row = blockIdx.x;
    int lane = threadIdx.x;
    const float4v v = *(const float4v*)(x + (size_t)row * NUM_FEATURES + lane * 4);
    float s = v.x * v.x + v.y * v.y + v.z * v.z + v.w * v.w;
    s = wave_reduce_sum(s);
    float scale = 1.0f / fmaxf(sqrtf(s), EPSF);
    float4v nv = v * scale;
    *(float4v*)(xn + (size_t)row * NUM_FEATURES + lane * 4) = nv;
    short4v bv;
    bv.x = f2bf(nv.x); bv.y = f2bf(nv.y); bv.z = f2bf(nv.z); bv.w = f2bf(nv.w);
    *(short4v*)(xnb + (size_t)row * NUM_FEATURES + lane * 4) = bv;
    if (lane == 0) out_tgt[row] = (float)tgt[row];
}

// ---------------------------------------------------------------------------
// K2: per weight row: copy raw row -> out_w (new_weight baseline), and write
// normalized bf16 row -> wnb (GEMM B operand). 4 waves/block, 1 row/wave.
__global__ __launch_bounds__(256) void wnorm_kernel(const float* __restrict__ w,
                                                    short* __restrict__ wnb,
                                                    float* __restrict__ out_w) {
    int row = blockIdx.x * 4 + (threadIdx.x >> 6);
    int lane = threadIdx.x & 63;
    const float4v v = *(const float4v*)(w + (size_t)row * NUM_FEATURES + lane * 4);
    float s = v.x * v.x + v.y * v.y + v.z * v.z + v.w * v.w;
    s = wave_reduce_sum(s);
    float scale = 1.0f / fmaxf(sqrtf(s), EPSF);
    // raw copy (un-normalized), per reference: untouched rows keep raw values
    *(float4v*)(out_w + (size_t)row * NUM_FEATURES + lane * 4) = v;
    float4v nv = v * scale;
    short4v bv;
    bv.x = f2bf(nv.x); bv.y = f2bf(nv.y); bv.z = f2bf(nv.z); bv.w = f2bf(nv.w);
    *(short4v*)(wnb + (size_t)row * NUM_FEATURES + lane * 4) = bv;
}

// ---------------------------------------------------------------------------
// K3: per-sample duplicate-target chains. head[i]=1 iff no j<i with same
// target; nxt[i] = first j>i with same target, else -1. O(B^2) trivial.
__global__ __launch_bounds__(1024) void chain_kernel(const int* __restrict__ tgt,
                                                     int* __restrict__ head,
                                                     int* __restrict__ nxt) {
    __shared__ int t[BATCH];
    int i = threadIdx.x;
    t[i] = tgt[i];
    __syncthreads();
    int mine = t[i];
    int h = 1;
    for (int j = 0; j < i; ++j)
        if (t[j] == mine) { h = 0; break; }
    int nx = -1;
    for (int j = i + 1; j < BATCH; ++j)
        if (t[j] == mine) { nx = j; break; }
    head[i] = h;
    nxt[i] = nx;
}

// ---------------------------------------------------------------------------
// K4: apply momentum updates. One wave per chain head; replay chain in batch
// order in fp32 (exactly matches the sequential reference semantics because
// distinct targets are independent and only the final row state is stored).
__global__ __launch_bounds__(64) void update_kernel(const float* __restrict__ xn,
                                                    const float* __restrict__ w_raw,
                                                    const int* __restrict__ tgt,
                                                    const int* __restrict__ head,
                                                    const int* __restrict__ nxt,
                                                    float* __restrict__ out_w) {
    int i = blockIdx.x;
    if (!head[i]) return;
    int lane = threadIdx.x;
    int t = tgt[i];
    float4v row = *(const float4v*)(w_raw + (size_t)t * NUM_FEATURES + lane * 4);
    int cur = i;
    while (cur >= 0) {
        const float4v xv = *(const float4v*)(xn + (size_t)cur * NUM_FEATURES + lane * 4);
        row = row * 0.5f + xv * 0.5f;
        float s = row.x * row.x + row.y * row.y + row.z * row.z + row.w * row.w;
        s = wave_reduce_sum(s);
        float scale = 1.0f / fmaxf(sqrtf(s), EPSF);
        row = row * scale;
        cur = nxt[cur];
    }
    *(float4v*)(out_w + (size_t)t * NUM_FEATURES + lane * 4) = row;
}

// ---------------------------------------------------------------------------
// K5: predicts = (xn @ wnb^T) * 30. Write-bound GEMM: M=1024, N=100000, K=256.
// 128x128 block tile, 4 waves in 2x2, each wave 64x64 via 16 mfma 16x16x32.
// No LDS: A (512 KB) is L2-hot, B (51.2 MB) is L3-resident and read by the 8
// co-scheduled M-blocks (blockIdx.x fastest = M so same-N blocks are adjacent).
__global__ __launch_bounds__(256) void gemm_kernel(const short* __restrict__ xnb,
                                                   const short* __restrict__ wnb,
                                                   float* __restrict__ out) {
    int tid = threadIdx.x;
    int lane = tid & 63;
    int wave = tid >> 6;
    int wm = wave & 1;
    int wn = wave >> 1;
    int m0 = blockIdx.x * 128 + wm * 64;   // M = 1024 exactly divisible
    int n0 = blockIdx.y * 128 + wn * 64;   // N tail guarded
    int r16 = lane & 15;   // row-within-16-tile for both A and B operands
    int quad = lane >> 4;  // k-chunk selector (8 elems = 16 B)

    float4v acc[4][4];
#pragma unroll
    for (int i = 0; i < 4; ++i)
#pragma unroll
        for (int j = 0; j < 4; ++j) acc[i][j] = (float4v){0.f, 0.f, 0.f, 0.f};

    // precompute clamped B row indices (tail tile reads row 99999, discarded at store)
    int nrow[4];
#pragma unroll
    for (int j = 0; j < 4; ++j) {
        int n = n0 + j * 16 + r16;
        nrow[j] = n < NUM_CLASSES ? n : (NUM_CLASSES - 1);
    }
    int arow[4];
#pragma unroll
    for (int i = 0; i < 4; ++i) arow[i] = m0 + i * 16 + r16;

    for (int s = 0; s < 8; ++s) {  // K = 8 steps of 32
        int k0 = s * 32 + quad * 8;
        short8 a[4], b[4];
#pragma unroll
        for (int i = 0; i < 4; ++i)
            a[i] = *(const short8*)(xnb + (size_t)arow[i] * NUM_FEATURES + k0);
#pragma unroll
        for (int j = 0; j < 4; ++j)
            b[j] = *(const short8*)(wnb + (size_t)nrow[j] * NUM_FEATURES + k0);
#pragma unroll
        for (int i = 0; i < 4; ++i)
#pragma unroll
            for (int j = 0; j < 4; ++j)
                acc[i][j] = __builtin_amdgcn_mfma_f32_16x16x32_bf16(a[i], b[j], acc[i][j], 0, 0, 0);
    }

    // C/D layout: col = lane&15, row = (lane>>4)*4 + reg
#pragma unroll
    for (int i = 0; i < 4; ++i) {
#pragma unroll
        for (int j = 0; j < 4; ++j) {
            int n = n0 + j * 16 + r16;
            if (n < NUM_CLASSES) {
#pragma unroll
                for (int r = 0; r < 4; ++r) {
                    int m = m0 + i * 16 + quad * 4 + r;
                    out[(size_t)m * NUM_CLASSES + n] = acc[i][j][r] * SCALARF;
                }
            }
        }
    }
}

// ---------------------------------------------------------------------------
extern "C" void kernel_launch(void* const* d_in, const int* in_sizes, int n_in,
                              void* d_out, int out_size, void* d_ws, size_t ws_size,
                              hipStream_t stream) {
    const float* x = (const float*)d_in[0];     // [1024, 256] f32
    const int* tgt = (const int*)d_in[1];       // [1024] i32
    const float* w = (const float*)d_in[2];     // [100000, 256] f32

    float* out = (float*)d_out;
    float* out_pred = out;                                    // [1024, 100000]
    float* out_tgt = out + (size_t)BATCH * NUM_CLASSES;       // [1024] (as f32 values)
    float* out_w = out_tgt + BATCH;                           // [100000, 256]

    char* ws = (char*)d_ws;
    float* xn = (float*)ws;                                   // 1 MB fp32 x_norm
    short* xnb = (short*)(ws + (1 << 20));                    // 512 KB bf16 x_norm
    short* wnb = (short*)(ws + (1 << 20) + (1 << 19));        // 51.2 MB bf16 w_norm
    int* head = (int*)(ws + (1 << 20) + (1 << 19) + (size_t)NUM_CLASSES * NUM_FEATURES * 2);
    int* nxt = head + BATCH;

    xnorm_kernel<<<BATCH, 64, 0, stream>>>(x, tgt, xn, xnb, out_tgt);
    wnorm_kernel<<<NUM_CLASSES / 4, 256, 0, stream>>>(w, wnb, out_w);
    chain_kernel<<<1, BATCH, 0, stream>>>(tgt, head, nxt);
    update_kernel<<<BATCH, 64, 0, stream>>>(xn, w, tgt, head, nxt, out_w);
    dim3 grid(BATCH / 128, (NUM_CLASSES + 127) / 128);  // (8, 782), x fastest = M
    gemm_kernel<<<grid, 256, 0, stream>>>(xnb, wnb, out_pred);
}